// Round 1
// baseline (485.020 us; speedup 1.0000x reference)
//
#include <hip/hip_runtime.h>
#include <stdint.h>

#define I_SIZE 256
#define D_DIM 128
#define BATCH 1024
#define S_LDS 136            // padded LDS row stride in bf16 elems (16B multiple: 136*2=272)
#define THREADS 512
#define CHUNKS 2
#define ROWS_PER_CHUNK (BATCH / CHUNKS)          // 512
#define ROWS_PER_PASS 128                        // 8 waves * 16 rows
#define PASSES (ROWS_PER_CHUNK / ROWS_PER_PASS)  // 4

typedef __attribute__((ext_vector_type(8))) short short8;
typedef __attribute__((ext_vector_type(4))) short short4v;
typedef __attribute__((ext_vector_type(4))) float floatx4;

__device__ inline short f2bf(float f) {
    union { float f; uint32_t u; } v; v.f = f;
    uint32_t u = v.u;
    uint32_t r = (u + 0x7FFFu + ((u >> 16) & 1u)) >> 16;   // RNE
    return (short)(r & 0xFFFFu);
}
__device__ inline float bf2f(short s) {
    union { uint32_t u; float f; } v; v.u = ((uint32_t)(uint16_t)s) << 16;
    return v.f;
}
__device__ inline float sigmoidf_fast(float x) { return 1.0f / (1.0f + __expf(-x)); }
__device__ inline float tanhf_fast(float x)    { return 2.0f / (1.0f + __expf(-2.0f * x)) - 1.0f; }

__global__ __launch_bounds__(THREADS, 2) void gru_kernel(
    const float* __restrict__ X, const float* __restrict__ H,
    const float* __restrict__ Wr, const float* __restrict__ Wz, const float* __restrict__ Wh,
    const float* __restrict__ Ur, const float* __restrict__ Uz, const float* __restrict__ Uh,
    const float* __restrict__ br, const float* __restrict__ bz, const float* __restrict__ bh,
    float* __restrict__ out)
{
    // Ut[g][n*S + j] = U_g[group][j][n] as bf16 (transposed so B-frags are ds_read_b128)
    __shared__ short Ut[3][D_DIM * S_LDS];            // 3 * 34816 B = 104448 B
    __shared__ short hgb[ROWS_PER_PASS * S_LDS];      // 34816 B (hg tile, later overwritten by p=r*hg)
    __shared__ float Wl[6][D_DIM];                    // Wr,Wz,Wh,br,bz,bh (3072 B)

    const int tid   = threadIdx.x;
    const int group = blockIdx.x & 255;
    const int chunk = blockIdx.x >> 8;
    const int batch0 = chunk * ROWS_PER_CHUNK;

    if (tid < D_DIM) {
        Wl[0][tid] = Wr[group * D_DIM + tid];
        Wl[1][tid] = Wz[group * D_DIM + tid];
        Wl[2][tid] = Wh[group * D_DIM + tid];
        Wl[3][tid] = br[group * D_DIM + tid];
        Wl[4][tid] = bz[group * D_DIM + tid];
        Wl[5][tid] = bh[group * D_DIM + tid];
    }

    // ---- stage U_r,U_z,U_h transposed into LDS as bf16 ----
    {
        const int jj = tid >> 5;          // 0..15
        const int k0 = (tid & 31) * 4;    // 0..124
        const float* Us0 = Ur + (size_t)group * (D_DIM * D_DIM);
        const float* Us1 = Uz + (size_t)group * (D_DIM * D_DIM);
        const float* Us2 = Uh + (size_t)group * (D_DIM * D_DIM);
        #pragma unroll
        for (int g = 0; g < 3; ++g) {
            const float* Ug = (g == 0) ? Us0 : (g == 1) ? Us1 : Us2;
            for (int rep = 0; rep < 8; ++rep) {
                int j = rep * 16 + jj;
                float4 v = *(const float4*)(Ug + j * D_DIM + k0);
                Ut[g][(k0 + 0) * S_LDS + j] = f2bf(v.x);
                Ut[g][(k0 + 1) * S_LDS + j] = f2bf(v.y);
                Ut[g][(k0 + 2) * S_LDS + j] = f2bf(v.z);
                Ut[g][(k0 + 3) * S_LDS + j] = f2bf(v.w);
            }
        }
    }
    __syncthreads();

    const int lane = tid & 63;
    const int wave = tid >> 6;          // 0..7
    const int am   = lane & 15;         // A row / B col(n) / C col
    const int aq   = lane >> 4;         // quad
    const int r0   = wave * 16;         // this wave's private row block within the pass
    const size_t HOFF = (size_t)BATCH * I_SIZE * D_DIM;   // h_tilde output offset

    for (int pass = 0; pass < PASSES; ++pass) {
        const int R = batch0 + pass * ROWS_PER_PASS;      // global batch row base

        // ---- stage this wave's 16 rows of hg -> LDS bf16 ----
        {
            const int rowp = lane >> 5;         // 0..1
            const int col4 = (lane & 31) * 4;   // 0..124
            #pragma unroll
            for (int it = 0; it < 8; ++it) {
                int rl = r0 + it * 2 + rowp;
                const float* src = H + (size_t)(R + rl) * (I_SIZE * D_DIM) + group * D_DIM + col4;
                float4 v = *(const float4*)src;
                short4v s;
                s.x = f2bf(v.x); s.y = f2bf(v.y); s.z = f2bf(v.z); s.w = f2bf(v.w);
                *(short4v*)&hgb[rl * S_LDS + col4] = s;
            }
        }
        __syncthreads();

        // ---- A-fragments (hg) ----
        short8 a[4];
        #pragma unroll
        for (int kk = 0; kk < 4; ++kk)
            a[kk] = *(const short8*)&hgb[(r0 + am) * S_LDS + kk * 32 + aq * 8];

        // ---- r and z GEMMs ----
        floatx4 zero = {0.f, 0.f, 0.f, 0.f};
        floatx4 accr[8], accz[8];
        #pragma unroll
        for (int t = 0; t < 8; ++t) { accr[t] = zero; accz[t] = zero; }

        #pragma unroll
        for (int t = 0; t < 8; ++t) {
            const int nbase = (t * 16 + am) * S_LDS + aq * 8;
            #pragma unroll
            for (int kk = 0; kk < 4; ++kk) {
                short8 bf = *(const short8*)&Ut[0][nbase + kk * 32];
                accr[t] = __builtin_amdgcn_mfma_f32_16x16x32_bf16(a[kk], bf, accr[t], 0, 0, 0);
            }
            #pragma unroll
            for (int kk = 0; kk < 4; ++kk) {
                short8 bf = *(const short8*)&Ut[1][nbase + kk * 32];
                accz[t] = __builtin_amdgcn_mfma_f32_16x16x32_bf16(a[kk], bf, accz[t], 0, 0, 0);
            }
        }

        // ---- epilogue 1: r,z gates; p = r*hg written in place (each addr owned by one lane) ----
        float Xv[4];
        #pragma unroll
        for (int pp = 0; pp < 4; ++pp)
            Xv[pp] = X[(size_t)(R + r0 + aq * 4 + pp) * I_SIZE + group];

        float zr[8][4], hgc[8][4];
        #pragma unroll
        for (int t = 0; t < 8; ++t) {
            const int c = t * 16 + am;
            const float wr = Wl[0][c], wz = Wl[1][c], brv = Wl[3][c], bzv = Wl[4][c];
            #pragma unroll
            for (int pp = 0; pp < 4; ++pp) {
                const int rl = r0 + aq * 4 + pp;
                float hgv = bf2f(hgb[rl * S_LDS + c]);
                float rv = sigmoidf_fast(accr[t][pp] + Xv[pp] * wr + brv);
                float zv = sigmoidf_fast(accz[t][pp] + Xv[pp] * wz + bzv);
                zr[t][pp]  = zv;
                hgc[t][pp] = hgv;
                hgb[rl * S_LDS + c] = f2bf(rv * hgv);
            }
        }
        __syncthreads();

        // ---- h GEMM: A = p = r*hg ----
        short8 ap[4];
        #pragma unroll
        for (int kk = 0; kk < 4; ++kk)
            ap[kk] = *(const short8*)&hgb[(r0 + am) * S_LDS + kk * 32 + aq * 8];

        floatx4 acch[8];
        #pragma unroll
        for (int t = 0; t < 8; ++t) acch[t] = zero;
        #pragma unroll
        for (int t = 0; t < 8; ++t) {
            const int nbase = (t * 16 + am) * S_LDS + aq * 8;
            #pragma unroll
            for (int kk = 0; kk < 4; ++kk) {
                short8 bf = *(const short8*)&Ut[2][nbase + kk * 32];
                acch[t] = __builtin_amdgcn_mfma_f32_16x16x32_bf16(ap[kk], bf, acch[t], 0, 0, 0);
            }
        }

        // ---- epilogue 2: h_tilde, h_new, store ----
        #pragma unroll
        for (int t = 0; t < 8; ++t) {
            const int c = t * 16 + am;
            const float wh = Wl[2][c], bhv = Wl[5][c];
            #pragma unroll
            for (int pp = 0; pp < 4; ++pp) {
                const int rl = r0 + aq * 4 + pp;
                float ht = tanhf_fast(acch[t][pp] + Xv[pp] * wh + bhv);
                float zv = zr[t][pp];
                float hn = zv * hgc[t][pp] + (1.0f - zv) * ht;
                size_t o = (size_t)(R + rl) * (I_SIZE * D_DIM) + group * D_DIM + c;
                out[o]        = hn;
                out[HOFF + o] = ht;
            }
        }
        __syncthreads();   // hgb reused next pass
    }
}

extern "C" void kernel_launch(void* const* d_in, const int* in_sizes, int n_in,
                              void* d_out, int out_size, void* d_ws, size_t ws_size,
                              hipStream_t stream) {
    const float* X  = (const float*)d_in[0];
    const float* H  = (const float*)d_in[1];
    const float* Wr = (const float*)d_in[2];
    const float* Wz = (const float*)d_in[3];
    const float* Wh = (const float*)d_in[4];
    const float* Ur = (const float*)d_in[5];
    const float* Uz = (const float*)d_in[6];
    const float* Uh = (const float*)d_in[7];
    const float* br = (const float*)d_in[8];
    const float* bz = (const float*)d_in[9];
    const float* bh = (const float*)d_in[10];

    gru_kernel<<<dim3(I_SIZE * CHUNKS), dim3(THREADS), 0, stream>>>(
        X, H, Wr, Wz, Wh, Ur, Uz, Uh, br, bz, bh, (float*)d_out);
}

// Round 2
// 473.870 us; speedup vs baseline: 1.0235x; 1.0235x over previous
//
#include <hip/hip_runtime.h>
#include <hip/hip_bf16.h>
#include <stdint.h>

#define I_SIZE 256
#define D_DIM 128
#define BATCH 1024

typedef __attribute__((ext_vector_type(8))) short short8;
typedef __attribute__((ext_vector_type(4))) short short4v;
typedef __attribute__((ext_vector_type(4))) float floatx4;

__device__ inline short f2bf(float f) {
    union { float f; uint32_t u; } v; v.f = f;
    uint32_t u = v.u;
    uint32_t r = (u + 0x7FFFu + ((u >> 16) & 1u)) >> 16;   // RNE
    return (short)(r & 0xFFFFu);
}
__device__ inline float bf2f(short s) {
    union { uint32_t u; float f; } v; v.u = ((uint32_t)(uint16_t)s) << 16;
    return v.f;
}
__device__ inline uint32_t pkbf(float a, float b) {
    __hip_bfloat162 h = __float22bfloat162_rn(make_float2(a, b));
    union { __hip_bfloat162 h; uint32_t u; } v; v.h = h; return v.u;
}
__device__ inline float sigmoidf_fast(float x) { return 1.0f / (1.0f + __expf(-x)); }
__device__ inline float tanhf_fast(float x)    { return 2.0f / (1.0f + __expf(-2.0f * x)) - 1.0f; }

// ============================================================================
// Pre-kernel: U[g][grp][j][k] fp32  ->  ws bf16, transposed (row n=k, content j)
// with XOR swizzle: element j of row n stored at p*8 + (j&7), p=(j>>3)^(n&7).
// This makes the main kernel's LDS image DMA-copyable (contiguous) AND
// conflict-free for b128 B-fragment reads without padding.
// ============================================================================
__global__ __launch_bounds__(256) void transpose_u(
    const float* __restrict__ Ur, const float* __restrict__ Uz,
    const float* __restrict__ Uh, short* __restrict__ ws)
{
    __shared__ short tile[D_DIM * D_DIM];   // 32 KB swizzled bf16 image
    const int grp = blockIdx.x;
    const int g   = blockIdx.y;
    const float* Ug = ((g == 0) ? Ur : (g == 1) ? Uz : Uh) + (size_t)grp * (D_DIM * D_DIM);
    const int t = threadIdx.x;
    const int lane = t & 63;
    const int w = t >> 6;

    for (int m = 0; m < 16; ++m) {
        int j0 = w + 4 * (m >> 1);          // 0..31
        int k  = lane + 64 * (m & 1);       // 0..127  (coalesced across lanes)
        float a0 = Ug[(4 * j0 + 0) * D_DIM + k];
        float a1 = Ug[(4 * j0 + 1) * D_DIM + k];
        float a2 = Ug[(4 * j0 + 2) * D_DIM + k];
        float a3 = Ug[(4 * j0 + 3) * D_DIM + k];
        short4v s; s.x = f2bf(a0); s.y = f2bf(a1); s.z = f2bf(a2); s.w = f2bf(a3);
        int p = (j0 >> 1) ^ (k & 7);
        *(short4v*)&tile[k * D_DIM + p * 8 + 4 * (j0 & 1)] = s;   // b64 write
    }
    __syncthreads();
    short* dst = ws + ((size_t)g * I_SIZE + grp) * (D_DIM * D_DIM);
    for (int q = 0; q < 8; ++q) {
        int off = q * 2048 + t * 8;         // shorts; lanes contiguous, b128 both sides
        *(short8*)(dst + off) = *(const short8*)&tile[off];
    }
}

// ============================================================================
// Main kernel: 256 blocks (1/group), 1024 threads (16 waves, 4/SIMD).
// Waves: rowgroup = w>>1 (16 rows), n-half = w&1 (64 cols).
// ============================================================================
#define S_H 136   // hgb stride in shorts: rows 16B-aligned, A-frag b128 conflict-free

__global__ __launch_bounds__(1024, 4) void gru_main(
    const float* __restrict__ X, const float* __restrict__ H,
    const float* __restrict__ Wr, const float* __restrict__ Wz, const float* __restrict__ Wh,
    const float* __restrict__ br, const float* __restrict__ bz, const float* __restrict__ bh,
    const short* __restrict__ Utg, float* __restrict__ out)
{
    __shared__ short Ut[3 * D_DIM * D_DIM];   // 98304 B swizzled bf16 U^T
    __shared__ short hgb[D_DIM * S_H];        // 34816 B hg tile (later p = r*hg)
    __shared__ float Wl[6][D_DIM];            // 3072 B

    const int tid   = threadIdx.x;
    const int group = blockIdx.x;
    const int lane  = tid & 63;
    const int w     = tid >> 6;

    if (tid < D_DIM) {
        Wl[0][tid] = Wr[group * D_DIM + tid];
        Wl[1][tid] = Wz[group * D_DIM + tid];
        Wl[2][tid] = Wh[group * D_DIM + tid];
        Wl[3][tid] = br[group * D_DIM + tid];
        Wl[4][tid] = bz[group * D_DIM + tid];
        Wl[5][tid] = bh[group * D_DIM + tid];
    }

    // ---- stage all three U^T images via async global->LDS DMA (96 x 1KB) ----
    {
        #pragma unroll
        for (int q = 0; q < 6; ++q) {
            int chunk = w * 6 + q;                    // 0..95
            int g   = chunk >> 5;
            int off = (chunk & 31) * 1024;            // bytes within g-image
            const char* gp = (const char*)Utg + ((size_t)g * I_SIZE + group) * 32768
                             + off + lane * 16;
            char* lp = ((char*)Ut) + g * 32768 + off; // wave-uniform base
            __builtin_amdgcn_global_load_lds(
                (const __attribute__((address_space(1))) void*)gp,
                (__attribute__((address_space(3))) void*)lp, 16, 0, 0);
        }
    }
    __syncthreads();

    const int am = lane & 15;
    const int aq = lane >> 4;
    const int rg = w >> 1;           // row group 0..7
    const int nh = w & 1;            // n-half
    const int r0 = rg * 16;
    const size_t HOFF = (size_t)BATCH * I_SIZE * D_DIM;
    const int srow = tid >> 3;           // staging row 0..127
    const int scol = (tid & 7) * 4;      // staging col base

    int pswz[4];
    #pragma unroll
    for (int kk = 0; kk < 4; ++kk) pswz[kk] = ((4 * kk + aq) ^ (am & 7)) * 8;

    const floatx4 zero = {0.f, 0.f, 0.f, 0.f};

    for (int pass = 0; pass < 8; ++pass) {
        const int R = pass * 128;

        // ---- stage hg rows -> LDS bf16 (coalesced 128B/row-octet loads) ----
        #pragma unroll
        for (int it = 0; it < 4; ++it) {
            int col = scol + it * 32;
            float4 v = *(const float4*)(H + (size_t)(R + srow) * (I_SIZE * D_DIM)
                                        + group * D_DIM + col);
            uint2 uu; uu.x = pkbf(v.x, v.y); uu.y = pkbf(v.z, v.w);
            *(uint2*)&hgb[srow * S_H + col] = uu;
        }
        __syncthreads();

        // ---- A fragments (hg) ----
        short8 a[4];
        #pragma unroll
        for (int kk = 0; kk < 4; ++kk)
            a[kk] = *(const short8*)&hgb[(r0 + am) * S_H + kk * 32 + aq * 8];

        // ---- r and z GEMMs (this wave's 64-col half) ----
        floatx4 accr[4], accz[4];
        #pragma unroll
        for (int t2 = 0; t2 < 4; ++t2) { accr[t2] = zero; accz[t2] = zero; }

        #pragma unroll
        for (int t2 = 0; t2 < 4; ++t2) {
            const int n = nh * 64 + t2 * 16 + am;
            const short* rowp = &Ut[n * D_DIM];
            #pragma unroll
            for (int kk = 0; kk < 4; ++kk)
                accr[t2] = __builtin_amdgcn_mfma_f32_16x16x32_bf16(
                    a[kk], *(const short8*)(rowp + pswz[kk]), accr[t2], 0, 0, 0);
            #pragma unroll
            for (int kk = 0; kk < 4; ++kk)
                accz[t2] = __builtin_amdgcn_mfma_f32_16x16x32_bf16(
                    a[kk], *(const short8*)(rowp + 16384 + pswz[kk]), accz[t2], 0, 0, 0);
        }

        // ---- epilogue 1: r,z gates; p = r*hg in place ----
        float Xv[4];
        #pragma unroll
        for (int pp = 0; pp < 4; ++pp)
            Xv[pp] = X[(size_t)(R + r0 + aq * 4 + pp) * I_SIZE + group];

        float zr[4][4], hgc[4][4];
        #pragma unroll
        for (int t2 = 0; t2 < 4; ++t2) {
            const int c = nh * 64 + t2 * 16 + am;
            const float wr = Wl[0][c], wz = Wl[1][c], brv = Wl[3][c], bzv = Wl[4][c];
            #pragma unroll
            for (int pp = 0; pp < 4; ++pp) {
                const int rl = r0 + aq * 4 + pp;
                float hgv = bf2f(hgb[rl * S_H + c]);
                float rv = sigmoidf_fast(accr[t2][pp] + Xv[pp] * wr + brv);
                float zv = sigmoidf_fast(accz[t2][pp] + Xv[pp] * wz + bzv);
                zr[t2][pp]  = zv;
                hgc[t2][pp] = hgv;
                hgb[rl * S_H + c] = f2bf(rv * hgv);
            }
        }
        __syncthreads();

        // ---- h GEMM: A = p = r*hg ----
        short8 ap[4];
        #pragma unroll
        for (int kk = 0; kk < 4; ++kk)
            ap[kk] = *(const short8*)&hgb[(r0 + am) * S_H + kk * 32 + aq * 8];

        floatx4 acch[4];
        #pragma unroll
        for (int t2 = 0; t2 < 4; ++t2) acch[t2] = zero;
        #pragma unroll
        for (int t2 = 0; t2 < 4; ++t2) {
            const int n = nh * 64 + t2 * 16 + am;
            const short* rowp = &Ut[32768 + n * D_DIM];
            #pragma unroll
            for (int kk = 0; kk < 4; ++kk)
                acch[t2] = __builtin_amdgcn_mfma_f32_16x16x32_bf16(
                    a[0] /*placeholder avoided*/, *(const short8*)(rowp + pswz[kk]), acch[t2], 0, 0, 0);
        }
        // NOTE: the line above must use ap[kk]; rewritten correctly below.
        #pragma unroll
        for (int t2 = 0; t2 < 4; ++t2) acch[t2] = zero;
        #pragma unroll
        for (int t2 = 0; t2 < 4; ++t2) {
            const int n = nh * 64 + t2 * 16 + am;
            const short* rowp = &Ut[32768 + n * D_DIM];
            #pragma unroll
            for (int kk = 0; kk < 4; ++kk)
                acch[t2] = __builtin_amdgcn_mfma_f32_16x16x32_bf16(
                    ap[kk], *(const short8*)(rowp + pswz[kk]), acch[t2], 0, 0, 0);
        }

        // ---- epilogue 2: h_tilde, h_new, store ----
        #pragma unroll
        for (int t2 = 0; t2 < 4; ++t2) {
            const int c = nh * 64 + t2 * 16 + am;
            const float wh = Wl[2][c], bhv = Wl[5][c];
            #pragma unroll
            for (int pp = 0; pp < 4; ++pp) {
                const int rl = r0 + aq * 4 + pp;
                float ht = tanhf_fast(acch[t2][pp] + Xv[pp] * wh + bhv);
                float zv = zr[t2][pp];
                float hn = zv * hgc[t2][pp] + (1.0f - zv) * ht;
                size_t o = (size_t)(R + rl) * (I_SIZE * D_DIM) + group * D_DIM + c;
                out[o]        = hn;
                out[HOFF + o] = ht;
            }
        }
        __syncthreads();   // hgb reused next pass
    }
}

// ============================================================================
// Fallback (round-1 kernel, known-passing) if ws_size < 25 MB
// ============================================================================
#define S_LDS 136
#define THREADS 512
#define CHUNKS 2
#define ROWS_PER_CHUNK (BATCH / CHUNKS)
#define ROWS_PER_PASS 128
#define PASSES (ROWS_PER_CHUNK / ROWS_PER_PASS)

__global__ __launch_bounds__(THREADS, 2) void gru_kernel(
    const float* __restrict__ X, const float* __restrict__ H,
    const float* __restrict__ Wr, const float* __restrict__ Wz, const float* __restrict__ Wh,
    const float* __restrict__ Ur, const float* __restrict__ Uz, const float* __restrict__ Uh,
    const float* __restrict__ br, const float* __restrict__ bz, const float* __restrict__ bh,
    float* __restrict__ out)
{
    __shared__ short Ut[3][D_DIM * S_LDS];
    __shared__ short hgb[ROWS_PER_PASS * S_LDS];
    __shared__ float Wl[6][D_DIM];

    const int tid   = threadIdx.x;
    const int group = blockIdx.x & 255;
    const int chunk = blockIdx.x >> 8;
    const int batch0 = chunk * ROWS_PER_CHUNK;

    if (tid < D_DIM) {
        Wl[0][tid] = Wr[group * D_DIM + tid];
        Wl[1][tid] = Wz[group * D_DIM + tid];
        Wl[2][tid] = Wh[group * D_DIM + tid];
        Wl[3][tid] = br[group * D_DIM + tid];
        Wl[4][tid] = bz[group * D_DIM + tid];
        Wl[5][tid] = bh[group * D_DIM + tid];
    }
    {
        const int jj = tid >> 5;
        const int k0 = (tid & 31) * 4;
        const float* Us0 = Ur + (size_t)group * (D_DIM * D_DIM);
        const float* Us1 = Uz + (size_t)group * (D_DIM * D_DIM);
        const float* Us2 = Uh + (size_t)group * (D_DIM * D_DIM);
        #pragma unroll
        for (int g = 0; g < 3; ++g) {
            const float* Ug = (g == 0) ? Us0 : (g == 1) ? Us1 : Us2;
            for (int rep = 0; rep < 8; ++rep) {
                int j = rep * 16 + jj;
                float4 v = *(const float4*)(Ug + j * D_DIM + k0);
                Ut[g][(k0 + 0) * S_LDS + j] = f2bf(v.x);
                Ut[g][(k0 + 1) * S_LDS + j] = f2bf(v.y);
                Ut[g][(k0 + 2) * S_LDS + j] = f2bf(v.z);
                Ut[g][(k0 + 3) * S_LDS + j] = f2bf(v.w);
            }
        }
    }
    __syncthreads();

    const int lane = tid & 63;
    const int wave = tid >> 6;
    const int am   = lane & 15;
    const int aq   = lane >> 4;
    const int r0   = wave * 16;
    const size_t HOFF = (size_t)BATCH * I_SIZE * D_DIM;

    for (int pass = 0; pass < PASSES; ++pass) {
        const int R = batch0 + pass * ROWS_PER_PASS;
        {
            const int rowp = lane >> 5;
            const int col4 = (lane & 31) * 4;
            #pragma unroll
            for (int it = 0; it < 8; ++it) {
                int rl = r0 + it * 2 + rowp;
                const float* src = H + (size_t)(R + rl) * (I_SIZE * D_DIM) + group * D_DIM + col4;
                float4 v = *(const float4*)src;
                short4v s;
                s.x = f2bf(v.x); s.y = f2bf(v.y); s.z = f2bf(v.z); s.w = f2bf(v.w);
                *(short4v*)&hgb[rl * S_LDS + col4] = s;
            }
        }
        __syncthreads();

        short8 a[4];
        #pragma unroll
        for (int kk = 0; kk < 4; ++kk)
            a[kk] = *(const short8*)&hgb[(r0 + am) * S_LDS + kk * 32 + aq * 8];

        floatx4 zero = {0.f, 0.f, 0.f, 0.f};
        floatx4 accr[8], accz[8];
        #pragma unroll
        for (int t = 0; t < 8; ++t) { accr[t] = zero; accz[t] = zero; }
        #pragma unroll
        for (int t = 0; t < 8; ++t) {
            const int nbase = (t * 16 + am) * S_LDS + aq * 8;
            #pragma unroll
            for (int kk = 0; kk < 4; ++kk)
                accr[t] = __builtin_amdgcn_mfma_f32_16x16x32_bf16(
                    a[kk], *(const short8*)&Ut[0][nbase + kk * 32], accr[t], 0, 0, 0);
            #pragma unroll
            for (int kk = 0; kk < 4; ++kk)
                accz[t] = __builtin_amdgcn_mfma_f32_16x16x32_bf16(
                    a[kk], *(const short8*)&Ut[1][nbase + kk * 32], accz[t], 0, 0, 0);
        }

        float Xv[4];
        #pragma unroll
        for (int pp = 0; pp < 4; ++pp)
            Xv[pp] = X[(size_t)(R + r0 + aq * 4 + pp) * I_SIZE + group];

        float zr[8][4], hgc[8][4];
        #pragma unroll
        for (int t = 0; t < 8; ++t) {
            const int c = t * 16 + am;
            const float wr = Wl[0][c], wz = Wl[1][c], brv = Wl[3][c], bzv = Wl[4][c];
            #pragma unroll
            for (int pp = 0; pp < 4; ++pp) {
                const int rl = r0 + aq * 4 + pp;
                float hgv = bf2f(hgb[rl * S_LDS + c]);
                float rv = sigmoidf_fast(accr[t][pp] + Xv[pp] * wr + brv);
                float zv = sigmoidf_fast(accz[t][pp] + Xv[pp] * wz + bzv);
                zr[t][pp]  = zv;
                hgc[t][pp] = hgv;
                hgb[rl * S_LDS + c] = f2bf(rv * hgv);
            }
        }
        __syncthreads();

        short8 ap[4];
        #pragma unroll
        for (int kk = 0; kk < 4; ++kk)
            ap[kk] = *(const short8*)&hgb[(r0 + am) * S_LDS + kk * 32 + aq * 8];

        floatx4 acch[8];
        #pragma unroll
        for (int t = 0; t < 8; ++t) acch[t] = zero;
        #pragma unroll
        for (int t = 0; t < 8; ++t) {
            const int nbase = (t * 16 + am) * S_LDS + aq * 8;
            #pragma unroll
            for (int kk = 0; kk < 4; ++kk)
                acch[t] = __builtin_amdgcn_mfma_f32_16x16x32_bf16(
                    ap[kk], *(const short8*)&Ut[2][nbase + kk * 32], acch[t], 0, 0, 0);
        }
        #pragma unroll
        for (int t = 0; t < 8; ++t) {
            const int c = t * 16 + am;
            const float wh = Wl[2][c], bhv = Wl[5][c];
            #pragma unroll
            for (int pp = 0; pp < 4; ++pp) {
                const int rl = r0 + aq * 4 + pp;
                float ht = tanhf_fast(acch[t][pp] + Xv[pp] * wh + bhv);
                float zv = zr[t][pp];
                float hn = zv * hgc[t][pp] + (1.0f - zv) * ht;
                size_t o = (size_t)(R + rl) * (I_SIZE * D_DIM) + group * D_DIM + c;
                out[o]        = hn;
                out[HOFF + o] = ht;
            }
        }
        __syncthreads();
    }
}

extern "C" void kernel_launch(void* const* d_in, const int* in_sizes, int n_in,
                              void* d_out, int out_size, void* d_ws, size_t ws_size,
                              hipStream_t stream) {
    const float* X  = (const float*)d_in[0];
    const float* H  = (const float*)d_in[1];
    const float* Wr = (const float*)d_in[2];
    const float* Wz = (const float*)d_in[3];
    const float* Wh = (const float*)d_in[4];
    const float* Ur = (const float*)d_in[5];
    const float* Uz = (const float*)d_in[6];
    const float* Uh = (const float*)d_in[7];
    const float* br = (const float*)d_in[8];
    const float* bz = (const float*)d_in[9];
    const float* bh = (const float*)d_in[10];

    const size_t need = (size_t)3 * I_SIZE * D_DIM * D_DIM * sizeof(short); // 25165824
    if (ws_size >= need) {
        transpose_u<<<dim3(I_SIZE, 3), dim3(256), 0, stream>>>(Ur, Uz, Uh, (short*)d_ws);
        gru_main<<<dim3(I_SIZE), dim3(1024), 0, stream>>>(
            X, H, Wr, Wz, Wh, br, bz, bh, (const short*)d_ws, (float*)d_out);
    } else {
        gru_kernel<<<dim3(I_SIZE * CHUNKS), dim3(THREADS), 0, stream>>>(
            X, H, Wr, Wz, Wh, Ur, Uz, Uh, br, bz, bh, (float*)d_out);
    }
}